// Round 6
// baseline (123.219 us; speedup 1.0000x reference)
//
#include <hip/hip_runtime.h>
#include <hip/hip_cooperative_groups.h>

namespace cg = cooperative_groups;

// Pairwise-KL abs-diff loss, N=128, D=4096, f32.
// loss = (1e-4 + sum_{i,j} |c[i] - M[i,j]|) / (N*N)
//   M[i,j] = sum_d ( s[i,d]*log s[j,d] - t[i,d]*log t[j,d] )
//   KEY IDENTITY: KL(p||p)=0 => c[i] = M[i,i] — read the self term off the
//   diagonal of the summed partials; no separate self-term pass.
//
// FUSED single cooperative kernel (round 6): phase 1 = cross tiles (identical
// code to the verified round-3/5 cross_kernel), grid.sync(), phase 2 = finish
// on blocks 0..127 (identical code to the verified finish_kernel). Motivation:
// round-3->5 A/B showed dur_us is dominated by fixed harness work (256 MiB ws
// poison fill ~41us @82% HBM + restores); removing a whole finisher phase
// moved only -0.9us, so remaining addressable cost is our ~5us of kernels +
// per-node graph gaps. Fusing removes one node (launch slot + tail + gap).
//
// Phase 1: 4 output tiles (64x64) x 128 d-chunks (32 d) = 512 blocks, 256 thr,
//   2 blocks/CU co-resident (36 KiB LDS, <=4 fit; cooperative launch
//   guarantees it). Stages s/t (i-rows) and log s/log t (j-rows) transposed
//   into LDS [d][row] (PAD 68, 16B-aligned). 4x4 micro-tile per thread via
//   float4 LDS reads: A-side 16-lane broadcast (bank-dedup), B-side 2-way
//   wrap (free, m136) -> VALU-bound (~1024 v_fma/thread). Per-chunk partial M
//   to ws (8 MiB, deterministic stores).
// Phase 2 (bx<128): sum 128 chunk partials of row bx (coalesced), ci =
//   diagonal, sum_j |ci - tot[j]|, block reduce, one atomicAdd. Block 0 adds
//   1e-4/N^2 and zeroed *out in phase 1 (visible after grid sync).

#define DIM 4096
#define NROWS 128
#define BK 32    // d per chunk
#define BT 64    // output tile dim
#define NCH 128  // chunks = DIM/BK
#define PAD 68   // 68*4 B = 272 B row pitch, 16B aligned

__global__ __launch_bounds__(256) void fused_kernel(
    const float* __restrict__ S, const float* __restrict__ T,
    float* __restrict__ Mpart, float* __restrict__ out)
{
    __shared__ float sS[BK][PAD];
    __shared__ float sT[BK][PAD];
    __shared__ float sLS[BK][PAD];
    __shared__ float sLT[BK][PAD];
    __shared__ float red[256];
    __shared__ float tot[NROWS];

    const int bx   = blockIdx.x;
    const int tile = bx & 3;      // ti*2 + tj
    const int ch   = bx >> 2;     // 0..127
    const int ti = tile >> 1, tj = tile & 1;
    const int i0 = ti * BT;
    const int j0 = tj * BT;
    const int c0 = ch * BK;
    const int tid = threadIdx.x;

    if (bx == 0 && tid == 0) *out = 0.f;   // d_out re-poisoned before every call

    // ---- Phase 1: cross tile (identical to verified cross_kernel) ----
    #pragma unroll
    for (int rep = 0; rep < 2; ++rep) {
        const int f   = tid + rep * 256;   // 0..511
        const int row = f >> 3;            // 0..63
        const int dq  = (f & 7) << 2;      // 0,4,...,28

        float4 v;
        v = *(const float4*)(S + (size_t)(i0 + row) * DIM + c0 + dq);
        sS[dq + 0][row] = v.x; sS[dq + 1][row] = v.y;
        sS[dq + 2][row] = v.z; sS[dq + 3][row] = v.w;

        v = *(const float4*)(T + (size_t)(i0 + row) * DIM + c0 + dq);
        sT[dq + 0][row] = v.x; sT[dq + 1][row] = v.y;
        sT[dq + 2][row] = v.z; sT[dq + 3][row] = v.w;

        v = *(const float4*)(S + (size_t)(j0 + row) * DIM + c0 + dq);
        sLS[dq + 0][row] = __logf(v.x); sLS[dq + 1][row] = __logf(v.y);
        sLS[dq + 2][row] = __logf(v.z); sLS[dq + 3][row] = __logf(v.w);

        v = *(const float4*)(T + (size_t)(j0 + row) * DIM + c0 + dq);
        sLT[dq + 0][row] = __logf(v.x); sLT[dq + 1][row] = __logf(v.y);
        sLT[dq + 2][row] = __logf(v.z); sLT[dq + 3][row] = __logf(v.w);
    }
    __syncthreads();

    const int il4 = (tid >> 4) << 2;   // i within tile; 16-lane broadcast
    const int jl4 = (tid & 15) << 2;   // j within tile; contiguous

    float acc[4][4];
    #pragma unroll
    for (int a = 0; a < 4; ++a)
        #pragma unroll
        for (int b = 0; b < 4; ++b) acc[a][b] = 0.f;

    #pragma unroll 4
    for (int d = 0; d < BK; ++d) {
        const float4 av = *(const float4*)&sS[d][il4];
        const float4 tv = *(const float4*)&sT[d][il4];
        const float4 bv = *(const float4*)&sLS[d][jl4];
        const float4 uv = *(const float4*)&sLT[d][jl4];
        const float A[4] = {av.x, av.y, av.z, av.w};
        const float Tt[4] = {tv.x, tv.y, tv.z, tv.w};
        const float B[4] = {bv.x, bv.y, bv.z, bv.w};
        const float U[4] = {uv.x, uv.y, uv.z, uv.w};
        #pragma unroll
        for (int a = 0; a < 4; ++a)
            #pragma unroll
            for (int b = 0; b < 4; ++b)
                acc[a][b] += A[a] * B[b] - Tt[a] * U[b];
    }

    {
        float* dst = Mpart + (size_t)ch * (NROWS * NROWS);
        #pragma unroll
        for (int a = 0; a < 4; ++a) {
            const float4 v = make_float4(acc[a][0], acc[a][1], acc[a][2], acc[a][3]);
            *(float4*)(dst + (size_t)(i0 + il4 + a) * NROWS + (j0 + jl4)) = v;
        }
    }

    // ---- Grid-wide sync: all partials device-visible ----
    cg::this_grid().sync();

    // ---- Phase 2: finish on blocks 0..127 (identical to verified finish_kernel) ----
    if (bx >= NROWS) return;
    const int i = bx;

    const int j = tid & 127;
    const int h = tid >> 7;        // 0..1, 64 chunks each
    float sum = 0.f;
    const float* mp = Mpart + (size_t)h * 64 * (NROWS * NROWS)
                    + (size_t)i * NROWS + j;
    #pragma unroll 8
    for (int chn = 0; chn < 64; ++chn)
        sum += mp[(size_t)chn * (NROWS * NROWS)];
    red[tid] = sum;
    __syncthreads();
    if (tid < NROWS) tot[tid] = red[tid] + red[tid + NROWS];
    __syncthreads();

    const float ci = tot[i];       // c[i] = M[i,i]
    red[tid] = (tid < NROWS) ? fabsf(ci - tot[tid]) : 0.f;
    __syncthreads();
    #pragma unroll
    for (int s = 128; s > 0; s >>= 1) {
        if (tid < s) red[tid] += red[tid + s];
        __syncthreads();
    }
    if (tid == 0) {
        float add = red[0] * (1.0f / 16384.0f);
        if (i == 0) add += 1e-4f / 16384.0f;
        atomicAdd(out, add);
    }
}

extern "C" void kernel_launch(void* const* d_in, const int* in_sizes, int n_in,
                              void* d_out, int out_size, void* d_ws, size_t ws_size,
                              hipStream_t stream) {
    const float* S = (const float*)d_in[0];   // new_source [128][4096] f32
    const float* T = (const float*)d_in[1];   // new_target [128][4096] f32
    float* out   = (float*)d_out;             // scalar f32
    float* Mpart = (float*)d_ws;              // 128 chunks x 128 x 128 f32 = 8 MiB

    void* args[] = { (void*)&S, (void*)&T, (void*)&Mpart, (void*)&out };
    hipLaunchCooperativeKernel((const void*)fused_kernel,
                               dim3(512), dim3(256), args, 0, stream);
}

// Round 10
// 69.621 us; speedup vs baseline: 1.7698x; 1.7698x over previous
//
#include <hip/hip_runtime.h>

// Pairwise-KL abs-diff loss, N=128, D=4096, f32.
// loss = (1e-4 + sum_{i,j} |c[i] - M[i,j]|) / (N*N)
//   M[i,j] = sum_d ( s[i,d]*log s[j,d] - t[i,d]*log t[j,d] )
//   KL(p||p)=0 => c[i] = M[i,i]: self term read off the diagonal.
//
// ROUND LOG:
//  r3/r5 two-kernel: 71.4 / 70.5 us; top-5 all harness 256MiB ws-poison fills
//    (~41us @82% HBM) => fixed floor ~65us (fill + restores + graph slots);
//    our kernels ~5us (r6 profile: VALUBusy 6% of 55us => ~3.4us VALU).
//  r6 cooperative fusion: FAILED (123us; fused kernel 55us, WRITE_SIZE
//    8.2MB->HBM). grid.sync across 8 non-coherent XCDs = L2 writeback + HBM
//    barrier spin. Reverted.
//  r9: COMPILE FAIL — __builtin_nontemporal_store rejects HIP float4
//    (HIP_vector_type class, not a clang vector). Fixed here: store via
//    ext_vector_type(4) float alias (same 16B layout, same dwordx4 + nt bit).
//  r10 (this): two-kernel + (a) nontemporal Mpart stores, (b) XCD-grouping
//    swizzle (4 tile-blocks sharing a chunk's 32KB input slice -> same XCD L2;
//    bijective: bx=(((ch&15)<<2|tile)<<3)|(ch>>4)), (c) finish 512 thr /
//    4-way chunk split.
//  CEILING: if this lands ~70 (flat vs r5), remaining time is harness resets
//    + launch floor -> addressable roofline reached.

#define DIM 4096
#define NROWS 128
#define BK 32    // d per chunk
#define BT 64    // output tile dim
#define NCH 128  // chunks = DIM/BK
#define PAD 68   // 68*4 B = 272 B row pitch, 16B aligned

typedef float vfloat4 __attribute__((ext_vector_type(4)));  // clang-native for nt builtin

__global__ __launch_bounds__(256) void cross_kernel(
    const float* __restrict__ S, const float* __restrict__ T,
    float* __restrict__ Mpart, float* __restrict__ out)
{
    __shared__ float sS[BK][PAD];
    __shared__ float sT[BK][PAD];
    __shared__ float sLS[BK][PAD];
    __shared__ float sLT[BK][PAD];

    const int bx = blockIdx.x;
    // XCD-grouping swizzle: dispatch i lands on XCD i%8. Give XCD x chunks
    // 16x..16x+15, with the 4 tile-blocks of each chunk consecutive on that
    // XCD -> 4x L2 reuse of the chunk's input slice. Bijective remap.
    const int x    = bx & 7;
    const int r    = bx >> 3;            // 0..63
    const int ch   = (x << 4) | (r >> 2); // 0..127
    const int tile = r & 3;              // ti*2 + tj
    const int ti = tile >> 1, tj = tile & 1;
    const int i0 = ti * BT;
    const int j0 = tj * BT;
    const int c0 = ch * BK;
    const int tid = threadIdx.x;

    if (bx == 0 && tid == 0) *out = 0.f;   // d_out re-poisoned before every call

    // Stage: per matrix 64 rows x 32 d = 512 float4 loads; 2 per thread.
    #pragma unroll
    for (int rep = 0; rep < 2; ++rep) {
        const int f   = tid + rep * 256;   // 0..511
        const int row = f >> 3;            // 0..63
        const int dq  = (f & 7) << 2;      // 0,4,...,28

        float4 v;
        v = *(const float4*)(S + (size_t)(i0 + row) * DIM + c0 + dq);
        sS[dq + 0][row] = v.x; sS[dq + 1][row] = v.y;
        sS[dq + 2][row] = v.z; sS[dq + 3][row] = v.w;

        v = *(const float4*)(T + (size_t)(i0 + row) * DIM + c0 + dq);
        sT[dq + 0][row] = v.x; sT[dq + 1][row] = v.y;
        sT[dq + 2][row] = v.z; sT[dq + 3][row] = v.w;

        v = *(const float4*)(S + (size_t)(j0 + row) * DIM + c0 + dq);
        sLS[dq + 0][row] = __logf(v.x); sLS[dq + 1][row] = __logf(v.y);
        sLS[dq + 2][row] = __logf(v.z); sLS[dq + 3][row] = __logf(v.w);

        v = *(const float4*)(T + (size_t)(j0 + row) * DIM + c0 + dq);
        sLT[dq + 0][row] = __logf(v.x); sLT[dq + 1][row] = __logf(v.y);
        sLT[dq + 2][row] = __logf(v.z); sLT[dq + 3][row] = __logf(v.w);
    }
    __syncthreads();

    const int il4 = (tid >> 4) << 2;   // i within tile; 16-lane broadcast
    const int jl4 = (tid & 15) << 2;   // j within tile; contiguous

    float acc[4][4];
    #pragma unroll
    for (int a = 0; a < 4; ++a)
        #pragma unroll
        for (int b = 0; b < 4; ++b) acc[a][b] = 0.f;

    #pragma unroll 4
    for (int d = 0; d < BK; ++d) {
        const float4 av = *(const float4*)&sS[d][il4];
        const float4 tv = *(const float4*)&sT[d][il4];
        const float4 bv = *(const float4*)&sLS[d][jl4];
        const float4 uv = *(const float4*)&sLT[d][jl4];
        const float A[4] = {av.x, av.y, av.z, av.w};
        const float Tt[4] = {tv.x, tv.y, tv.z, tv.w};
        const float B[4] = {bv.x, bv.y, bv.z, bv.w};
        const float U[4] = {uv.x, uv.y, uv.z, uv.w};
        #pragma unroll
        for (int a = 0; a < 4; ++a)
            #pragma unroll
            for (int b = 0; b < 4; ++b)
                acc[a][b] += A[a] * B[b] - Tt[a] * U[b];
    }

    // Nontemporal export: write-once data read by the next kernel; streaming
    // stores avoid leaving 8 MiB dirty in L2 (r6 showed it spills to HBM anyway).
    float* dst = Mpart + (size_t)ch * (NROWS * NROWS);
    #pragma unroll
    for (int a = 0; a < 4; ++a) {
        vfloat4 v;
        v.x = acc[a][0]; v.y = acc[a][1]; v.z = acc[a][2]; v.w = acc[a][3];
        __builtin_nontemporal_store(v,
            (vfloat4*)(dst + (size_t)(i0 + il4 + a) * NROWS + (j0 + jl4)));
    }
}

__global__ __launch_bounds__(512) void finish_kernel(
    const float* __restrict__ Mpart, float* __restrict__ out)
{
    __shared__ float red[512];
    __shared__ float tot[NROWS];
    const int i   = blockIdx.x;    // output row 0..127
    const int tid = threadIdx.x;

    // Sum the 128 chunk partials of row i (4-way split per column j).
    const int j = tid & 127;
    const int q = tid >> 7;        // 0..3, 32 chunks each
    float sum = 0.f;
    const float* mp = Mpart + (size_t)q * 32 * (NROWS * NROWS)
                    + (size_t)i * NROWS + j;
    #pragma unroll 8
    for (int chn = 0; chn < 32; ++chn)
        sum += mp[(size_t)chn * (NROWS * NROWS)];
    red[tid] = sum;
    __syncthreads();
    if (tid < NROWS)
        tot[tid] = red[tid] + red[tid + 128] + red[tid + 256] + red[tid + 384];
    __syncthreads();

    // c[i] = M[i,i] (diagonal identity). Row contribution: sum_j |c[i]-M[i,j]|.
    const float ci = tot[i];
    red[tid] = (tid < NROWS) ? fabsf(ci - tot[tid]) : 0.f;
    __syncthreads();
    #pragma unroll
    for (int s = 128; s > 0; s >>= 1) {
        if (tid < s) red[tid] += red[tid + s];
        __syncthreads();
    }
    if (tid == 0) {
        float add = red[0] * (1.0f / 16384.0f);
        if (i == 0) add += 1e-4f / 16384.0f;
        atomicAdd(out, add);
    }
}

extern "C" void kernel_launch(void* const* d_in, const int* in_sizes, int n_in,
                              void* d_out, int out_size, void* d_ws, size_t ws_size,
                              hipStream_t stream) {
    const float* S = (const float*)d_in[0];   // new_source [128][4096] f32
    const float* T = (const float*)d_in[1];   // new_target [128][4096] f32
    float* out   = (float*)d_out;             // scalar f32
    float* Mpart = (float*)d_ws;              // 128 chunks x 128 x 128 f32 = 8 MiB

    cross_kernel<<<dim3(512), dim3(256), 0, stream>>>(S, T, Mpart, out);
    finish_kernel<<<dim3(128), dim3(512), 0, stream>>>(Mpart, out);
}